// Round 6
// baseline (1447.083 us; speedup 1.0000x reference)
//
#include <hip/hip_runtime.h>
#include <hip/hip_bf16.h>

// ---------------------------------------------------------------------------
// GCN 5-layer forward on MI355X (gfx950).
//   - CSR build (incoming edges per dst)
//   - layer 0 GEMM: fp32 x staged via LDS as split bf16 (pipelined)
//   - aggregation: s = dinv[i]*(g[i] + sum_s g[s]) + bias, ReLU; output
//     written as split bf16 (hi/lo) = next GEMM's A operand (non-temporal)
//     Wide layers (0-2) aggregate in 2 column passes to shrink the L3
//     working set of the random gather.
//   - layers 1-4 GEMM: pre-split bf16 A staged via LDS (pipelined)
// Padded feature dims: 512, 224, 192, 128, 96, 64.
// ---------------------------------------------------------------------------

typedef float f32x4 __attribute__((ext_vector_type(4)));
typedef short bf16x8 __attribute__((ext_vector_type(8)));
typedef ushort u16x4 __attribute__((ext_vector_type(4)));
typedef ushort u16x8 __attribute__((ext_vector_type(8)));

static const int GDIMS[6] = {512, 200, 175, 125, 75, 50};

// ---------------- graph preprocessing ----------------

__global__ void zero_kernel(int* __restrict__ p, int n) {
    int i = blockIdx.x * blockDim.x + threadIdx.x;
    for (; i < n; i += gridDim.x * blockDim.x) p[i] = 0;
}

__global__ void hist_kernel(const int* __restrict__ dst, int E, int* __restrict__ deg) {
    int i = blockIdx.x * blockDim.x + threadIdx.x;
    for (; i < E; i += gridDim.x * blockDim.x) atomicAdd(&deg[dst[i]], 1);
}

__global__ __launch_bounds__(1024) void scan_kernel(const int* __restrict__ deg,
                                                    int* __restrict__ rowptr, int N) {
    __shared__ int sums[1024];
    int t = threadIdx.x;
    int chunk = (N + 1023) >> 10;
    int lo = t * chunk;
    int hi = lo + chunk; if (hi > N) hi = N;
    if (lo > N) lo = N;
    int s = 0;
    for (int i = lo; i < hi; ++i) s += deg[i];
    sums[t] = s;
    __syncthreads();
    for (int off = 1; off < 1024; off <<= 1) {
        int v = (t >= off) ? sums[t - off] : 0;
        __syncthreads();
        sums[t] += v;
        __syncthreads();
    }
    int run = (t > 0) ? sums[t - 1] : 0;
    for (int i = lo; i < hi; ++i) { rowptr[i] = run; run += deg[i]; }
    if (t == 1023) rowptr[N] = run;
}

__global__ void dinv_kernel(const int* __restrict__ deg, float* __restrict__ dinv, int N) {
    int i = blockIdx.x * blockDim.x + threadIdx.x;
    for (; i < N; i += gridDim.x * blockDim.x)
        dinv[i] = rsqrtf((float)(deg[i] + 1));  // +1 self loop
}

__global__ void copy_kernel(const int* __restrict__ a, int* __restrict__ b, int n) {
    int i = blockIdx.x * blockDim.x + threadIdx.x;
    for (; i < n; i += gridDim.x * blockDim.x) b[i] = a[i];
}

__global__ void scatter_kernel(const int* __restrict__ src, const int* __restrict__ dst,
                               int E, int* __restrict__ cursor, int* __restrict__ csrc) {
    int i = blockIdx.x * blockDim.x + threadIdx.x;
    for (; i < E; i += gridDim.x * blockDim.x) {
        int d = dst[i];
        int pos = atomicAdd(&cursor[d], 1);
        csrc[pos] = src[i];
    }
}

// ---------------- weight pre-transpose + split ----------------

__global__ void wsplit_kernel(const float* __restrict__ W, int K, int Nout,
                              int Kp, ushort* __restrict__ Whi, ushort* __restrict__ Wlo) {
    int k = blockIdx.x * blockDim.x + threadIdx.x;
    int n = blockIdx.y;
    if (k >= Kp) return;
    float v = (k < K && n < Nout) ? W[(size_t)k * Nout + n] : 0.f;
    __bf16 h = (__bf16)v;
    ushort hb = __builtin_bit_cast(ushort, h);
    float hf = __builtin_bit_cast(float, (unsigned)hb << 16);
    __bf16 l = (__bf16)(v - hf);
    Whi[(size_t)n * Kp + k] = hb;
    Wlo[(size_t)n * Kp + k] = __builtin_bit_cast(ushort, l);
}

// ---------------- MFMA helpers ----------------

__device__ inline f32x4 mfma16(bf16x8 a, bf16x8 b, f32x4 c) {
    return __builtin_amdgcn_mfma_f32_16x16x32_bf16(a, b, c, 0, 0, 0);
}

__device__ inline void split8(f32x4 a0, f32x4 a1, u16x8& hi, u16x8& lo) {
    float af[8] = {a0[0], a0[1], a0[2], a0[3], a1[0], a1[1], a1[2], a1[3]};
#pragma unroll
    for (int e = 0; e < 8; ++e) {
        __bf16 h = (__bf16)af[e];
        ushort hb = __builtin_bit_cast(ushort, h);
        float hf = __builtin_bit_cast(float, (unsigned)hb << 16);
        __bf16 l = (__bf16)(af[e] - hf);
        hi[e] = hb;
        lo[e] = __builtin_bit_cast(ushort, l);
    }
}

// ---------------- layer-0 GEMM (fp32 A, LDS split, pipelined) ----------------

template<int WM, int WN>
__global__ __launch_bounds__(WM * WN * 64) void gemm_f32(
    const float* __restrict__ A, int lda, int Arows,
    const ushort* __restrict__ Bhi, const ushort* __restrict__ Blo, int Kp,
    const float* __restrict__ dinv, int N,
    float* __restrict__ C, int ldc)
{
    constexpr int BM = WM * 64;
    constexpr int T = WM * WN * 64;
    constexpr int SROW = BM + 2;
    constexpr int CH = BM * 4;
    constexpr int PT = (CH + T - 1) / T;
    __shared__ ushort Ah[4 * SROW * 8];
    __shared__ ushort Al[4 * SROW * 8];

    const int tid = threadIdx.x;
    const int lane = tid & 63;
    const int wave = tid >> 6;
    const int wm = (WM == 1) ? 0 : (wave % WM);
    const int wn = (WM == 1) ? wave : (wave / WM);
    const int m0 = blockIdx.x * BM;
    const int kg = lane >> 4;
    const int l16 = lane & 15;

    const ushort* bp[4];
#pragma unroll
    for (int fn = 0; fn < 4; ++fn) {
        int n = wn * 64 + fn * 16 + l16;
        bp[fn] = Bhi + (size_t)n * Kp + kg * 8;
    }
    const size_t lo_off = (size_t)(Blo - Bhi);

    f32x4 acc[4][4];
#pragma unroll
    for (int i = 0; i < 4; ++i)
#pragma unroll
        for (int j = 0; j < 4; ++j) acc[i][j] = (f32x4)0.f;

    f32x4 ra0[PT], ra1[PT];
#pragma unroll
    for (int p = 0; p < PT; ++p) {
        int j = tid + p * T;
        if (j < CH) {
            int row = j >> 2, jk = j & 3;
            int gr = m0 + row; if (gr > Arows - 1) gr = Arows - 1;
            const float* ap = A + (size_t)gr * lda + jk * 8;
            ra0[p] = *(const f32x4*)ap;
            ra1[p] = *(const f32x4*)(ap + 4);
        }
    }

    for (int k0 = 0; k0 < Kp; k0 += 32) {
#pragma unroll
        for (int p = 0; p < PT; ++p) {
            int j = tid + p * T;
            if (j < CH) {
                int row = j >> 2, jk = j & 3;
                u16x8 hi, lo;
                split8(ra0[p], ra1[p], hi, lo);
                int idx = (jk * SROW + row) * 8;
                *(u16x8*)&Ah[idx] = hi;
                *(u16x8*)&Al[idx] = lo;
            }
        }
        __syncthreads();
        if (k0 + 32 < Kp) {
#pragma unroll
            for (int p = 0; p < PT; ++p) {
                int j = tid + p * T;
                if (j < CH) {
                    int row = j >> 2, jk = j & 3;
                    int gr = m0 + row; if (gr > Arows - 1) gr = Arows - 1;
                    const float* ap = A + (size_t)gr * lda + (k0 + 32) + jk * 8;
                    ra0[p] = *(const f32x4*)ap;
                    ra1[p] = *(const f32x4*)(ap + 4);
                }
            }
        }

        bf16x8 bh[4], bl[4], ah[4], al[4];
#pragma unroll
        for (int fn = 0; fn < 4; ++fn) {
            bh[fn] = *(const bf16x8*)(bp[fn] + k0);
            bl[fn] = *(const bf16x8*)(bp[fn] + lo_off + k0);
        }
#pragma unroll
        for (int fm = 0; fm < 4; ++fm) {
            int idx = (kg * SROW + wm * 64 + fm * 16 + l16) * 8;
            ah[fm] = *(const bf16x8*)&Ah[idx];
            al[fm] = *(const bf16x8*)&Al[idx];
        }
#pragma unroll
        for (int fm = 0; fm < 4; ++fm)
#pragma unroll
            for (int fn = 0; fn < 4; ++fn) {
                acc[fm][fn] = mfma16(ah[fm], bh[fn], acc[fm][fn]);
                acc[fm][fn] = mfma16(ah[fm], bl[fn], acc[fm][fn]);
                acc[fm][fn] = mfma16(al[fm], bh[fn], acc[fm][fn]);
            }
        __syncthreads();
    }

#pragma unroll
    for (int fm = 0; fm < 4; ++fm)
#pragma unroll
        for (int fn = 0; fn < 4; ++fn) {
            int col = wn * 64 + fn * 16 + l16;
            if (col < ldc) {
#pragma unroll
                for (int r = 0; r < 4; ++r) {
                    int row = m0 + wm * 64 + fm * 16 + kg * 4 + r;
                    float dv = (row < N) ? dinv[row] : 0.f;
                    C[(size_t)row * ldc + col] = acc[fm][fn][r] * dv;
                }
            }
        }
}

// ---------- layers 1-4 GEMM (pre-split bf16 A, LDS staged, pipelined) ----------

template<int WM, int WN>
__global__ __launch_bounds__(WM * WN * 64) void gemm_pre(
    const ushort* __restrict__ Ahi, const ushort* __restrict__ Alo, int lda,
    const ushort* __restrict__ Bhi, const ushort* __restrict__ Blo, int Kp,
    const float* __restrict__ dinv, int N,
    float* __restrict__ C, int ldc)
{
    constexpr int BM = WM * 64;
    constexpr int T = WM * WN * 64;
    constexpr int SROW = BM + 2;
    constexpr int CH = BM * 4;
    constexpr int PT = (CH + T - 1) / T;
    __shared__ ushort Ah[4 * SROW * 8];
    __shared__ ushort Al[4 * SROW * 8];

    const int tid = threadIdx.x;
    const int lane = tid & 63;
    const int wave = tid >> 6;
    const int wm = (WM == 1) ? 0 : (wave % WM);
    const int wn = (WM == 1) ? wave : (wave / WM);
    const int m0 = blockIdx.x * BM;
    const int kg = lane >> 4;
    const int l16 = lane & 15;

    const size_t alo = (size_t)(Alo - Ahi);
    const ushort* bp[4];
#pragma unroll
    for (int fn = 0; fn < 4; ++fn) {
        int n = wn * 64 + fn * 16 + l16;
        bp[fn] = Bhi + (size_t)n * Kp + kg * 8;
    }
    const size_t blo = (size_t)(Blo - Bhi);

    f32x4 acc[4][4];
#pragma unroll
    for (int i = 0; i < 4; ++i)
#pragma unroll
        for (int j = 0; j < 4; ++j) acc[i][j] = (f32x4)0.f;

    u16x8 rh[PT], rl[PT];
#pragma unroll
    for (int p = 0; p < PT; ++p) {
        int j = tid + p * T;
        if (j < CH) {
            int row = j >> 2, jk = j & 3;
            const ushort* s = Ahi + (size_t)(m0 + row) * lda + jk * 8;
            rh[p] = *(const u16x8*)s;
            rl[p] = *(const u16x8*)(s + alo);
        }
    }

    for (int k0 = 0; k0 < Kp; k0 += 32) {
#pragma unroll
        for (int p = 0; p < PT; ++p) {
            int j = tid + p * T;
            if (j < CH) {
                int row = j >> 2, jk = j & 3;
                int idx = (jk * SROW + row) * 8;
                *(u16x8*)&Ah[idx] = rh[p];
                *(u16x8*)&Al[idx] = rl[p];
            }
        }
        __syncthreads();
        if (k0 + 32 < Kp) {
#pragma unroll
            for (int p = 0; p < PT; ++p) {
                int j = tid + p * T;
                if (j < CH) {
                    int row = j >> 2, jk = j & 3;
                    const ushort* s = Ahi + (size_t)(m0 + row) * lda + (k0 + 32) + jk * 8;
                    rh[p] = *(const u16x8*)s;
                    rl[p] = *(const u16x8*)(s + alo);
                }
            }
        }

        bf16x8 bh[4], bl[4], ah[4], al[4];
#pragma unroll
        for (int fn = 0; fn < 4; ++fn) {
            bh[fn] = *(const bf16x8*)(bp[fn] + k0);
            bl[fn] = *(const bf16x8*)(bp[fn] + blo + k0);
        }
#pragma unroll
        for (int fm = 0; fm < 4; ++fm) {
            int idx = (kg * SROW + wm * 64 + fm * 16 + l16) * 8;
            ah[fm] = *(const bf16x8*)&Ah[idx];
            al[fm] = *(const bf16x8*)&Al[idx];
        }
#pragma unroll
        for (int fm = 0; fm < 4; ++fm)
#pragma unroll
            for (int fn = 0; fn < 4; ++fn) {
                acc[fm][fn] = mfma16(ah[fm], bh[fn], acc[fm][fn]);
                acc[fm][fn] = mfma16(ah[fm], bl[fn], acc[fm][fn]);
                acc[fm][fn] = mfma16(al[fm], bh[fn], acc[fm][fn]);
            }
        __syncthreads();
    }

#pragma unroll
    for (int fm = 0; fm < 4; ++fm)
#pragma unroll
        for (int fn = 0; fn < 4; ++fn) {
            int col = wn * 64 + fn * 16 + l16;
            if (col < ldc) {
#pragma unroll
                for (int r = 0; r < 4; ++r) {
                    int row = m0 + wm * 64 + fm * 16 + kg * 4 + r;
                    float dv = (row < N) ? dinv[row] : 0.f;
                    C[(size_t)row * ldc + col] = acc[fm][fn][r] * dv;
                }
            }
        }
}

// ---------------- CSR aggregation (column-sliced) ----------------
// Processes column slice f4 in [f4base, f4base+ND4T). Non-temporal stores on
// outputs (read once later, streaming) to preserve L3 for the g gather.

template<int ND4T, bool FIN>
__global__ __launch_bounds__(256) void agg_t(
    const float* __restrict__ g, int ld4, int f4base,
    const int* __restrict__ rowptr, const int* __restrict__ csrc,
    const float* __restrict__ dinv, const float* __restrict__ bias,
    int D, int N,
    ushort* __restrict__ Ahi, ushort* __restrict__ Alo, int ldo,
    float* __restrict__ outF, int ldof)
{
    unsigned gt = blockIdx.x * 256u + threadIdx.x;
    unsigned node = gt / (unsigned)ND4T;
    unsigned f4 = f4base + (gt - node * (unsigned)ND4T);
    if (node >= (unsigned)N) return;

    const f32x4* g4 = (const f32x4*)g;
    const unsigned l4 = (unsigned)ld4;

    f32x4 a0 = g4[(size_t)node * l4 + f4];   // self term
    f32x4 a1 = (f32x4)0.f, a2 = (f32x4)0.f, a3 = (f32x4)0.f;
    f32x4 a4 = (f32x4)0.f, a5 = (f32x4)0.f, a6 = (f32x4)0.f, a7 = (f32x4)0.f;

    int beg = rowptr[node], end = rowptr[node + 1];
    int j = beg;
    for (; j + 7 < end; j += 8) {
        unsigned s0 = csrc[j],     s1 = csrc[j + 1], s2 = csrc[j + 2], s3 = csrc[j + 3];
        unsigned s4 = csrc[j + 4], s5 = csrc[j + 5], s6 = csrc[j + 6], s7 = csrc[j + 7];
        a0 += g4[(size_t)s0 * l4 + f4];
        a1 += g4[(size_t)s1 * l4 + f4];
        a2 += g4[(size_t)s2 * l4 + f4];
        a3 += g4[(size_t)s3 * l4 + f4];
        a4 += g4[(size_t)s4 * l4 + f4];
        a5 += g4[(size_t)s5 * l4 + f4];
        a6 += g4[(size_t)s6 * l4 + f4];
        a7 += g4[(size_t)s7 * l4 + f4];
    }
    for (; j + 3 < end; j += 4) {
        unsigned s0 = csrc[j], s1 = csrc[j + 1], s2 = csrc[j + 2], s3 = csrc[j + 3];
        a0 += g4[(size_t)s0 * l4 + f4];
        a1 += g4[(size_t)s1 * l4 + f4];
        a2 += g4[(size_t)s2 * l4 + f4];
        a3 += g4[(size_t)s3 * l4 + f4];
    }
    for (; j < end; ++j) a0 += g4[(size_t)csrc[j] * l4 + f4];

    f32x4 s = ((a0 + a1) + (a2 + a3)) + ((a4 + a5) + (a6 + a7));
    float di = dinv[node];

    if (FIN) {
#pragma unroll
        for (int e = 0; e < 4; ++e) {
            int f = (int)f4 * 4 + e;
            if (f < D)
                __builtin_nontemporal_store(fmaf(di, s[e], bias[f]),
                                            outF + (size_t)node * ldof + f);
        }
    } else {
        u16x4 hv, lv;
#pragma unroll
        for (int e = 0; e < 4; ++e) {
            int f = (int)f4 * 4 + e;
            float val = 0.f;
            if (f < D) val = fmaxf(fmaf(di, s[e], bias[f]), 0.f);
            __bf16 h = (__bf16)val;
            ushort hb = __builtin_bit_cast(ushort, h);
            float hf = __builtin_bit_cast(float, (unsigned)hb << 16);
            __bf16 l = (__bf16)(val - hf);
            hv[e] = hb;
            lv[e] = __builtin_bit_cast(ushort, l);
        }
        __builtin_nontemporal_store(hv, (u16x4*)(Ahi + (size_t)node * ldo + f4 * 4));
        __builtin_nontemporal_store(lv, (u16x4*)(Alo + (size_t)node * ldo + f4 * 4));
    }
}

// ---------------- host launcher ----------------

extern "C" void kernel_launch(void* const* d_in, const int* in_sizes, int n_in,
                              void* d_out, int out_size, void* d_ws, size_t ws_size,
                              hipStream_t stream) {
    const float* x = (const float*)d_in[0];
    const int* ei = (const int*)d_in[1];
    int E = in_sizes[1] / 2;
    int N = in_sizes[0] / GDIMS[0];
    int Mp = ((N + 255) / 256) * 256;
    const int* src = ei;
    const int* dst = ei + E;

    const float* W[5];
    const float* bia[5];
    for (int i = 0; i < 5; ++i) {
        W[i] = (const float*)d_in[2 + 2 * i];
        bia[i] = (const float*)d_in[3 + 2 * i];
    }

    char* ws = (char*)d_ws;
    size_t off = 0;
    auto alloc = [&](size_t bytes) -> void* {
        void* p = ws + off;
        off += (bytes + 255) & ~(size_t)255;
        return p;
    };
    int* deg = (int*)alloc((size_t)N * 4);
    int* rowptr = (int*)alloc((size_t)(N + 1) * 4);
    int* cursor = (int*)alloc((size_t)N * 4);
    float* dinv = (float*)alloc((size_t)N * 4);
    int* csrc = (int*)alloc((size_t)E * 4);
    float* g = (float*)alloc((size_t)Mp * 224 * 4);
    ushort* Ahi = (ushort*)alloc((size_t)Mp * 224 * 2);
    ushort* Alo = (ushort*)alloc((size_t)Mp * 224 * 2);
    ushort* Whi[5];
    ushort* Wlo[5];
    int NB[5] = {256, 192, 128, 128, 64};
    int KP[5] = {512, 224, 192, 128, 96};
    for (int l = 0; l < 5; ++l) {
        Whi[l] = (ushort*)alloc((size_t)NB[l] * KP[l] * 2);
        Wlo[l] = (ushort*)alloc((size_t)NB[l] * KP[l] * 2);
    }
    (void)ws_size;

    // graph preprocessing
    zero_kernel<<<1024, 256, 0, stream>>>(deg, N);
    hist_kernel<<<2048, 256, 0, stream>>>(dst, E, deg);
    scan_kernel<<<1, 1024, 0, stream>>>(deg, rowptr, N);
    dinv_kernel<<<512, 256, 0, stream>>>(deg, dinv, N);
    copy_kernel<<<512, 256, 0, stream>>>(rowptr, cursor, N);
    scatter_kernel<<<2048, 256, 0, stream>>>(src, dst, E, cursor, csrc);

    // weight split
    for (int l = 0; l < 5; ++l) {
        dim3 gw((KP[l] + 255) / 256, NB[l]);
        wsplit_kernel<<<gw, 256, 0, stream>>>(W[l], GDIMS[l], GDIMS[l + 1], KP[l],
                                              Whi[l], Wlo[l]);
    }

    auto aggBlocks = [&](int nd4t) { return (unsigned)(((size_t)N * nd4t + 255) / 256); };

    // ---- layer 0 (agg in 2 column passes: 2x28) ----
    gemm_f32<1, 4><<<Mp / 64, 256, 0, stream>>>(x, 512, N, Whi[0], Wlo[0], 512,
                                                dinv, N, g, 224);
    agg_t<28, false><<<aggBlocks(28), 256, 0, stream>>>(g, 56, 0, rowptr, csrc, dinv,
                                                        bia[0], 200, N, Ahi, Alo, 224,
                                                        nullptr, 0);
    agg_t<28, false><<<aggBlocks(28), 256, 0, stream>>>(g, 56, 28, rowptr, csrc, dinv,
                                                        bia[0], 200, N, Ahi, Alo, 224,
                                                        nullptr, 0);
    // ---- layer 1 (2x24) ----
    gemm_pre<1, 3><<<Mp / 64, 192, 0, stream>>>(Ahi, Alo, 224, Whi[1], Wlo[1], 224,
                                                dinv, N, g, 192);
    agg_t<24, false><<<aggBlocks(24), 256, 0, stream>>>(g, 48, 0, rowptr, csrc, dinv,
                                                        bia[1], 175, N, Ahi, Alo, 192,
                                                        nullptr, 0);
    agg_t<24, false><<<aggBlocks(24), 256, 0, stream>>>(g, 48, 24, rowptr, csrc, dinv,
                                                        bia[1], 175, N, Ahi, Alo, 192,
                                                        nullptr, 0);
    // ---- layer 2 (2x16) ----
    gemm_pre<2, 2><<<Mp / 128, 256, 0, stream>>>(Ahi, Alo, 192, Whi[2], Wlo[2], 192,
                                                 dinv, N, g, 128);
    agg_t<16, false><<<aggBlocks(16), 256, 0, stream>>>(g, 32, 0, rowptr, csrc, dinv,
                                                        bia[2], 125, N, Ahi, Alo, 128,
                                                        nullptr, 0);
    agg_t<16, false><<<aggBlocks(16), 256, 0, stream>>>(g, 32, 16, rowptr, csrc, dinv,
                                                        bia[2], 125, N, Ahi, Alo, 128,
                                                        nullptr, 0);
    // ---- layer 3 (single pass, A/B contrast) ----
    gemm_pre<2, 2><<<Mp / 128, 256, 0, stream>>>(Ahi, Alo, 128, Whi[3], Wlo[3], 128,
                                                 dinv, N, g, 96);
    agg_t<24, false><<<aggBlocks(24), 256, 0, stream>>>(g, 24, 0, rowptr, csrc, dinv,
                                                        bia[3], 75, N, Ahi, Alo, 96,
                                                        nullptr, 0);
    // ---- layer 4 (final, fp32 out, single pass) ----
    gemm_pre<4, 1><<<Mp / 256, 256, 0, stream>>>(Ahi, Alo, 96, Whi[4], Wlo[4], 96,
                                                 dinv, N, g, 64);
    agg_t<13, true><<<aggBlocks(13), 256, 0, stream>>>(g, 16, 0, rowptr, csrc, dinv,
                                                       bia[4], 50, N, nullptr, nullptr, 0,
                                                       (float*)d_out, 50);
    (void)out_size; (void)n_in;
}

// Round 7
// 1427.145 us; speedup vs baseline: 1.0140x; 1.0140x over previous
//
#include <hip/hip_runtime.h>
#include <hip/hip_bf16.h>

// ---------------------------------------------------------------------------
// GCN 5-layer forward on MI355X (gfx950).  Round-3 structure (best measured)
// + dbuf K64 GEMM for layers 0/1.
//   - CSR build (incoming edges per dst)
//   - per layer: split-bf16 MFMA GEMM (fp32 A staged via LDS as split bf16,
//     epilogue g = dinv*h), then CSR aggregation (fp32) with bias + ReLU.
//   - layers 0/1: gemm_d — double-buffered LDS, 1 barrier per 64-k tile,
//     next-tile loads issued before the MFMA cluster (issue-early/write-late)
//   - layers 2-4: gemm_t — simple 2-barrier K32 (small K, low register use)
// Padded feature dims: 512, 224, 192, 128, 96, 64.
// ---------------------------------------------------------------------------

typedef float f32x4 __attribute__((ext_vector_type(4)));
typedef short bf16x8 __attribute__((ext_vector_type(8)));
typedef ushort u16x8 __attribute__((ext_vector_type(8)));

static const int GDIMS[6] = {512, 200, 175, 125, 75, 50};

// ---------------- graph preprocessing ----------------

__global__ void zero_kernel(int* __restrict__ p, int n) {
    int i = blockIdx.x * blockDim.x + threadIdx.x;
    for (; i < n; i += gridDim.x * blockDim.x) p[i] = 0;
}

__global__ void hist_kernel(const int* __restrict__ dst, int E, int* __restrict__ deg) {
    int i = blockIdx.x * blockDim.x + threadIdx.x;
    for (; i < E; i += gridDim.x * blockDim.x) atomicAdd(&deg[dst[i]], 1);
}

__global__ __launch_bounds__(1024) void scan_kernel(const int* __restrict__ deg,
                                                    int* __restrict__ rowptr, int N) {
    __shared__ int sums[1024];
    int t = threadIdx.x;
    int chunk = (N + 1023) >> 10;
    int lo = t * chunk;
    int hi = lo + chunk; if (hi > N) hi = N;
    if (lo > N) lo = N;
    int s = 0;
    for (int i = lo; i < hi; ++i) s += deg[i];
    sums[t] = s;
    __syncthreads();
    for (int off = 1; off < 1024; off <<= 1) {
        int v = (t >= off) ? sums[t - off] : 0;
        __syncthreads();
        sums[t] += v;
        __syncthreads();
    }
    int run = (t > 0) ? sums[t - 1] : 0;
    for (int i = lo; i < hi; ++i) { rowptr[i] = run; run += deg[i]; }
    if (t == 1023) rowptr[N] = run;
}

__global__ void dinv_kernel(const int* __restrict__ deg, float* __restrict__ dinv, int N) {
    int i = blockIdx.x * blockDim.x + threadIdx.x;
    for (; i < N; i += gridDim.x * blockDim.x)
        dinv[i] = rsqrtf((float)(deg[i] + 1));  // +1 self loop
}

__global__ void copy_kernel(const int* __restrict__ a, int* __restrict__ b, int n) {
    int i = blockIdx.x * blockDim.x + threadIdx.x;
    for (; i < n; i += gridDim.x * blockDim.x) b[i] = a[i];
}

__global__ void scatter_kernel(const int* __restrict__ src, const int* __restrict__ dst,
                               int E, int* __restrict__ cursor, int* __restrict__ csrc) {
    int i = blockIdx.x * blockDim.x + threadIdx.x;
    for (; i < E; i += gridDim.x * blockDim.x) {
        int d = dst[i];
        int pos = atomicAdd(&cursor[d], 1);
        csrc[pos] = src[i];
    }
}

// ---------------- weight pre-transpose + split ----------------

__global__ void wsplit_kernel(const float* __restrict__ W, int K, int Nout,
                              int Kp, ushort* __restrict__ Whi, ushort* __restrict__ Wlo) {
    int k = blockIdx.x * blockDim.x + threadIdx.x;
    int n = blockIdx.y;
    if (k >= Kp) return;
    float v = (k < K && n < Nout) ? W[(size_t)k * Nout + n] : 0.f;
    __bf16 h = (__bf16)v;
    ushort hb = __builtin_bit_cast(ushort, h);
    float hf = __builtin_bit_cast(float, (unsigned)hb << 16);
    __bf16 l = (__bf16)(v - hf);
    Whi[(size_t)n * Kp + k] = hb;
    Wlo[(size_t)n * Kp + k] = __builtin_bit_cast(ushort, l);
}

// ---------------- MFMA helpers ----------------

__device__ inline f32x4 mfma16(bf16x8 a, bf16x8 b, f32x4 c) {
    return __builtin_amdgcn_mfma_f32_16x16x32_bf16(a, b, c, 0, 0, 0);
}

__device__ inline void split8(f32x4 a0, f32x4 a1, u16x8& hi, u16x8& lo) {
    float af[8] = {a0[0], a0[1], a0[2], a0[3], a1[0], a1[1], a1[2], a1[3]};
#pragma unroll
    for (int e = 0; e < 8; ++e) {
        __bf16 h = (__bf16)af[e];
        ushort hb = __builtin_bit_cast(ushort, h);
        float hf = __builtin_bit_cast(float, (unsigned)hb << 16);
        __bf16 l = (__bf16)(af[e] - hf);
        hi[e] = hb;
        lo[e] = __builtin_bit_cast(ushort, l);
    }
}

// ---------------- dbuf K64 GEMM (layers 0/1) ----------------
// BM = WM*64 rows x (WN*64) cols; K-tile 64 (two 32-k MFMA subs); LDS double
// buffered; ONE barrier per K-tile.  Next-tile global loads issue before the
// MFMA cluster; split+ds_write land after it (latency hidden under MFMA).

template<int WM, int WN>
__global__ __launch_bounds__(WM * WN * 64) void gemm_d(
    const float* __restrict__ A, int lda, int Arows,
    const ushort* __restrict__ Bhi, const ushort* __restrict__ Blo, int Kp,
    const float* __restrict__ dinv, int N,
    float* __restrict__ C, int ldc)
{
    constexpr int BM = WM * 64;
    constexpr int T = WM * WN * 64;
    constexpr int SROW = BM + 2;
    constexpr int NCH = BM * 8;            // (row, 8-k group) chunks per tile
    constexpr int PT = (NCH + T - 1) / T;
    constexpr int BUFS = 8 * SROW * 8;     // ushorts per buffer
    __shared__ ushort Ah[2 * BUFS];
    __shared__ ushort Al[2 * BUFS];

    const int tid = threadIdx.x;
    const int lane = tid & 63;
    const int wave = tid >> 6;
    const int wm = (WM == 1) ? 0 : (wave % WM);
    const int wn = (WM == 1) ? wave : (wave / WM);
    const int m0 = blockIdx.x * BM;
    const int kg = lane >> 4;
    const int l16 = lane & 15;

    const ushort* bp[4];
#pragma unroll
    for (int fn = 0; fn < 4; ++fn)
        bp[fn] = Bhi + (size_t)(wn * 64 + fn * 16 + l16) * Kp + kg * 8;
    const size_t blo = (size_t)(Blo - Bhi);

    f32x4 acc[4][4];
#pragma unroll
    for (int i = 0; i < 4; ++i)
#pragma unroll
        for (int j = 0; j < 4; ++j) acc[i][j] = (f32x4)0.f;

    // chunk descriptors
    const float* cap[PT];
    int cidx[PT], ckk[PT];
    bool cok[PT];
#pragma unroll
    for (int p = 0; p < PT; ++p) {
        int j = tid + p * T;
        cok[p] = j < NCH;
        int row = cok[p] ? (j >> 3) : 0;
        int jkq = cok[p] ? (j & 7) : 0;
        int gr = m0 + row; if (gr > Arows - 1) gr = Arows - 1;
        cap[p] = A + (size_t)gr * lda + jkq * 8;
        cidx[p] = (jkq * SROW + row) * 8;
        ckk[p] = jkq * 8;
    }

    // stage tile 0 into buffer 0
#pragma unroll
    for (int p = 0; p < PT; ++p) {
        if (cok[p]) {  // ckk < 64 <= Kp always
            f32x4 a0 = *(const f32x4*)(cap[p]);
            f32x4 a1 = *(const f32x4*)(cap[p] + 4);
            u16x8 hi, lo;
            split8(a0, a1, hi, lo);
            *(u16x8*)&Ah[cidx[p]] = hi;
            *(u16x8*)&Al[cidx[p]] = lo;
        }
    }
    __syncthreads();

    const int nIter = (Kp + 63) >> 6;
    f32x4 ra0[PT], ra1[PT];
    for (int it = 0; it < nIter; ++it) {
        const int buf = (it & 1) * BUFS;
        const int kbase = it << 6;
        const int nkb = kbase + 64;
        const bool hasNext = nkb < Kp;
        // 1) issue next-tile global loads (latency hides under MFMAs below)
        if (hasNext) {
#pragma unroll
            for (int p = 0; p < PT; ++p)
                if (cok[p] && nkb + ckk[p] < Kp) {
                    ra0[p] = *(const f32x4*)(cap[p] + nkb);
                    ra1[p] = *(const f32x4*)(cap[p] + nkb + 4);
                }
        }
        // 2) MFMA cluster on current buffer (up to 96 MFMAs)
#pragma unroll
        for (int s = 0; s < 2; ++s) {
            if (kbase + s * 32 >= Kp) break;
            bf16x8 ah[4], al4[4], bh[4], bl[4];
#pragma unroll
            for (int fn = 0; fn < 4; ++fn) {
                bh[fn] = *(const bf16x8*)(bp[fn] + kbase + s * 32);
                bl[fn] = *(const bf16x8*)(bp[fn] + blo + kbase + s * 32);
            }
#pragma unroll
            for (int fm = 0; fm < 4; ++fm) {
                int idx = buf + ((s * 4 + kg) * SROW + wm * 64 + fm * 16 + l16) * 8;
                ah[fm] = *(const bf16x8*)&Ah[idx];
                al4[fm] = *(const bf16x8*)&Al[idx];
            }
#pragma unroll
            for (int fm = 0; fm < 4; ++fm)
#pragma unroll
                for (int fn = 0; fn < 4; ++fn) {
                    acc[fm][fn] = mfma16(ah[fm], bh[fn], acc[fm][fn]);
                    acc[fm][fn] = mfma16(ah[fm], bl[fn], acc[fm][fn]);
                    acc[fm][fn] = mfma16(al4[fm], bh[fn], acc[fm][fn]);
                }
        }
        // 3) split + write next tile into other buffer
        if (hasNext) {
            const int obuf = buf ^ BUFS;
#pragma unroll
            for (int p = 0; p < PT; ++p)
                if (cok[p] && nkb + ckk[p] < Kp) {
                    u16x8 hi, lo;
                    split8(ra0[p], ra1[p], hi, lo);
                    *(u16x8*)&Ah[obuf + cidx[p]] = hi;
                    *(u16x8*)&Al[obuf + cidx[p]] = lo;
                }
        }
        __syncthreads();
    }

#pragma unroll
    for (int fm = 0; fm < 4; ++fm)
#pragma unroll
        for (int fn = 0; fn < 4; ++fn) {
            int col = wn * 64 + fn * 16 + l16;
            if (col < ldc) {
#pragma unroll
                for (int r = 0; r < 4; ++r) {
                    int row = m0 + wm * 64 + fm * 16 + kg * 4 + r;
                    float dv = (row < N) ? dinv[row] : 0.f;
                    C[(size_t)row * ldc + col] = acc[fm][fn][r] * dv;
                }
            }
        }
}

// ---------------- simple K32 GEMM (layers 2-4, round-3 proven) ----------------

template<int WM, int WN>
__global__ __launch_bounds__(WM * WN * 64) void gemm_t(
    const float* __restrict__ A, int lda, int Arows,
    const ushort* __restrict__ Bhi, const ushort* __restrict__ Blo, int Kp,
    const float* __restrict__ dinv, int N,
    float* __restrict__ C, int ldc)
{
    constexpr int BM = WM * 64;
    constexpr int T = WM * WN * 64;
    constexpr int SROW = BM + 2;
    __shared__ ushort Ah[4 * SROW * 8];
    __shared__ ushort Al[4 * SROW * 8];

    const int tid = threadIdx.x;
    const int lane = tid & 63;
    const int wave = tid >> 6;
    const int wm = (WM == 1) ? 0 : (wave % WM);
    const int wn = (WM == 1) ? wave : (wave / WM);
    const int m0 = blockIdx.x * BM;
    const int kg = lane >> 4;
    const int l16 = lane & 15;

    const ushort* bp[4];
#pragma unroll
    for (int fn = 0; fn < 4; ++fn) {
        int n = wn * 64 + fn * 16 + l16;
        bp[fn] = Bhi + (size_t)n * Kp + kg * 8;
    }
    const size_t lo_off = (size_t)(Blo - Bhi);

    f32x4 acc[4][4];
#pragma unroll
    for (int i = 0; i < 4; ++i)
#pragma unroll
        for (int j = 0; j < 4; ++j) acc[i][j] = (f32x4)0.f;

    for (int k0 = 0; k0 < Kp; k0 += 32) {
        for (int j = tid; j < BM * 4; j += T) {
            int row = j >> 2, jk = j & 3;
            int gr = m0 + row; if (gr > Arows - 1) gr = Arows - 1;
            const float* ap = A + (size_t)gr * lda + k0 + jk * 8;
            f32x4 a0 = *(const f32x4*)ap;
            f32x4 a1 = *(const f32x4*)(ap + 4);
            u16x8 hi, lo;
            split8(a0, a1, hi, lo);
            int idx = (jk * SROW + row) * 8;
            *(u16x8*)&Ah[idx] = hi;
            *(u16x8*)&Al[idx] = lo;
        }
        __syncthreads();
        bf16x8 bh[4], bl[4], ah[4], al[4];
#pragma unroll
        for (int fn = 0; fn < 4; ++fn) {
            bh[fn] = *(const bf16x8*)(bp[fn] + k0);
            bl[fn] = *(const bf16x8*)(bp[fn] + lo_off + k0);
        }
#pragma unroll
        for (int fm = 0; fm < 4; ++fm) {
            int idx = (kg * SROW + wm * 64 + fm * 16 + l16) * 8;
            ah[fm] = *(const bf16x8*)&Ah[idx];
            al[fm] = *(const bf16x8*)&Al[idx];
        }
#pragma unroll
        for (int fm = 0; fm < 4; ++fm)
#pragma unroll
            for (int fn = 0; fn < 4; ++fn) {
                acc[fm][fn] = mfma16(ah[fm], bh[fn], acc[fm][fn]);
                acc[fm][fn] = mfma16(ah[fm], bl[fn], acc[fm][fn]);
                acc[fm][fn] = mfma16(al[fm], bh[fn], acc[fm][fn]);
            }
        __syncthreads();
    }

#pragma unroll
    for (int fm = 0; fm < 4; ++fm)
#pragma unroll
        for (int fn = 0; fn < 4; ++fn) {
            int col = wn * 64 + fn * 16 + l16;
            if (col < ldc) {
#pragma unroll
                for (int r = 0; r < 4; ++r) {
                    int row = m0 + wm * 64 + fm * 16 + kg * 4 + r;
                    float dv = (row < N) ? dinv[row] : 0.f;
                    C[(size_t)row * ldc + col] = acc[fm][fn][r] * dv;
                }
            }
        }
}

// ---------------- CSR aggregation (round-3 proven) ----------------
// out[i][f] = relu( dinv[i]*(g[i][f] + sum_s g[s][f]) + b[f] ), g = dinv*h.

template<int L>
__global__ __launch_bounds__(256) void agg_t(
    const float* __restrict__ g, int ldg, int nd4,
    const int* __restrict__ rowptr, const int* __restrict__ csrc,
    const float* __restrict__ dinv, const float* __restrict__ bias,
    int D, int N, float* __restrict__ out, int ldo, int relu, int fin)
{
    int node = blockIdx.x * (256 / L) + threadIdx.x / L;
    if (node >= N) return;
    int f4 = threadIdx.x & (L - 1);
    if (f4 >= nd4) return;

    const f32x4* g4 = (const f32x4*)g;
    int ld4 = ldg >> 2;
    f32x4 a0 = g4[(size_t)node * ld4 + f4];   // self term
    f32x4 a1 = (f32x4)0.f, a2 = (f32x4)0.f, a3 = (f32x4)0.f;
    int beg = rowptr[node], end = rowptr[node + 1];
    int j = beg;
    for (; j + 3 < end; j += 4) {
        int s0 = csrc[j], s1 = csrc[j + 1], s2 = csrc[j + 2], s3 = csrc[j + 3];
        a0 += g4[(size_t)s0 * ld4 + f4];
        a1 += g4[(size_t)s1 * ld4 + f4];
        a2 += g4[(size_t)s2 * ld4 + f4];
        a3 += g4[(size_t)s3 * ld4 + f4];
    }
    for (; j < end; ++j) a0 += g4[(size_t)csrc[j] * ld4 + f4];

    f32x4 s = (a0 + a1) + (a2 + a3);
    float di = dinv[node];
    if (fin) {
#pragma unroll
        for (int e = 0; e < 4; ++e) {
            int f = f4 * 4 + e;
            if (f < D) out[(size_t)node * ldo + f] = fmaf(di, s[e], bias[f]);
        }
    } else {
        f32x4 v;
#pragma unroll
        for (int e = 0; e < 4; ++e) {
            int f = f4 * 4 + e;
            float val = (f < D) ? fmaf(di, s[e], bias[f]) : 0.f;
            if (relu) val = fmaxf(val, 0.f);
            v[e] = val;
        }
        *(f32x4*)(out + (size_t)node * ldo + f4 * 4) = v;
    }
}

// ---------------- host launcher ----------------

extern "C" void kernel_launch(void* const* d_in, const int* in_sizes, int n_in,
                              void* d_out, int out_size, void* d_ws, size_t ws_size,
                              hipStream_t stream) {
    const float* x = (const float*)d_in[0];
    const int* ei = (const int*)d_in[1];
    int E = in_sizes[1] / 2;
    int N = in_sizes[0] / GDIMS[0];
    int Mp = ((N + 255) / 256) * 256;
    const int* src = ei;
    const int* dst = ei + E;

    const float* W[5];
    const float* bia[5];
    for (int i = 0; i < 5; ++i) {
        W[i] = (const float*)d_in[2 + 2 * i];
        bia[i] = (const float*)d_in[3 + 2 * i];
    }

    char* ws = (char*)d_ws;
    size_t off = 0;
    auto alloc = [&](size_t bytes) -> void* {
        void* p = ws + off;
        off += (bytes + 255) & ~(size_t)255;
        return p;
    };
    int* deg = (int*)alloc((size_t)N * 4);
    int* rowptr = (int*)alloc((size_t)(N + 1) * 4);
    int* cursor = (int*)alloc((size_t)N * 4);
    float* dinv = (float*)alloc((size_t)N * 4);
    int* csrc = (int*)alloc((size_t)E * 4);
    float* g = (float*)alloc((size_t)Mp * 224 * 4);
    float* buf1 = (float*)alloc((size_t)Mp * 224 * 4);
    ushort* Whi[5];
    ushort* Wlo[5];
    int NB[5] = {256, 192, 128, 128, 64};
    int KP[5] = {512, 224, 192, 128, 96};
    for (int l = 0; l < 5; ++l) {
        Whi[l] = (ushort*)alloc((size_t)NB[l] * KP[l] * 2);
        Wlo[l] = (ushort*)alloc((size_t)NB[l] * KP[l] * 2);
    }
    (void)ws_size;

    // graph preprocessing
    zero_kernel<<<1024, 256, 0, stream>>>(deg, N);
    hist_kernel<<<2048, 256, 0, stream>>>(dst, E, deg);
    scan_kernel<<<1, 1024, 0, stream>>>(deg, rowptr, N);
    dinv_kernel<<<512, 256, 0, stream>>>(deg, dinv, N);
    copy_kernel<<<512, 256, 0, stream>>>(rowptr, cursor, N);
    scatter_kernel<<<2048, 256, 0, stream>>>(src, dst, E, cursor, csrc);

    // weight split
    for (int l = 0; l < 5; ++l) {
        dim3 gw((KP[l] + 255) / 256, NB[l]);
        wsplit_kernel<<<gw, 256, 0, stream>>>(W[l], GDIMS[l], GDIMS[l + 1], KP[l],
                                              Whi[l], Wlo[l]);
    }

    // ---- layer 0 ----
    gemm_d<1, 4><<<Mp / 64, 256, 0, stream>>>(x, 512, N, Whi[0], Wlo[0], 512,
                                              dinv, N, g, 224);
    agg_t<64><<<(N + 3) / 4, 256, 0, stream>>>(g, 224, 50, rowptr, csrc, dinv,
                                               bia[0], 200, N, buf1, 224, 1, 0);
    // ---- layer 1 ----
    gemm_d<1, 3><<<Mp / 64, 192, 0, stream>>>(buf1, 224, N, Whi[1], Wlo[1], 224,
                                              dinv, N, g, 192);
    agg_t<64><<<(N + 3) / 4, 256, 0, stream>>>(g, 192, 44, rowptr, csrc, dinv,
                                               bia[1], 175, N, buf1, 192, 1, 0);
    // ---- layer 2 ----
    gemm_t<2, 2><<<Mp / 128, 256, 0, stream>>>(buf1, 192, N, Whi[2], Wlo[2], 192,
                                               dinv, N, g, 128);
    agg_t<32><<<(N + 7) / 8, 256, 0, stream>>>(g, 128, 32, rowptr, csrc, dinv,
                                               bia[2], 125, N, buf1, 128, 1, 0);
    // ---- layer 3 ----
    gemm_t<2, 2><<<Mp / 128, 256, 0, stream>>>(buf1, 128, N, Whi[3], Wlo[3], 128,
                                               dinv, N, g, 96);
    agg_t<32><<<(N + 7) / 8, 256, 0, stream>>>(g, 96, 19, rowptr, csrc, dinv,
                                               bia[3], 75, N, buf1, 96, 1, 0);
    // ---- layer 4 (final, fp32 out) ----
    gemm_t<4, 1><<<Mp / 256, 256, 0, stream>>>(buf1, 96, N, Whi[4], Wlo[4], 96,
                                               dinv, N, g, 64);
    agg_t<16><<<(N + 15) / 16, 256, 0, stream>>>(g, 64, 13, rowptr, csrc, dinv,
                                                 bia[4], 50, N, (float*)d_out, 50, 0, 1);
    (void)out_size; (void)n_in;
}

// Round 8
// 1375.585 us; speedup vs baseline: 1.0520x; 1.0375x over previous
//
#include <hip/hip_runtime.h>
#include <hip/hip_bf16.h>

// ---------------------------------------------------------------------------
// GCN 5-layer forward on MI355X (gfx950).  Round-3 structure (best measured)
// + pre-split bf16 A handoff for layers 1-4 (removes split8 from k-loops).
//   - CSR build (incoming edges per dst)
//   - layer 0 GEMM: fp32 x staged via LDS as split bf16 (2-barrier K32)
//   - aggregation: s = dinv[i]*(g[i] + sum_s g[s]) + bias, ReLU; emits split
//     bf16 hi/lo (next GEMM's A) for layers 0-3, fp32 d_out for layer 4
//   - layers 1-4 GEMM: pre-split A, staging = pure 16B copies (2-barrier K32)
// Padded feature dims: 512, 224, 192, 128, 96, 64.
// ---------------------------------------------------------------------------

typedef float f32x4 __attribute__((ext_vector_type(4)));
typedef short bf16x8 __attribute__((ext_vector_type(8)));
typedef ushort u16x4 __attribute__((ext_vector_type(4)));
typedef ushort u16x8 __attribute__((ext_vector_type(8)));

static const int GDIMS[6] = {512, 200, 175, 125, 75, 50};

// ---------------- graph preprocessing ----------------

__global__ void zero_kernel(int* __restrict__ p, int n) {
    int i = blockIdx.x * blockDim.x + threadIdx.x;
    for (; i < n; i += gridDim.x * blockDim.x) p[i] = 0;
}

__global__ void hist_kernel(const int* __restrict__ dst, int E, int* __restrict__ deg) {
    int i = blockIdx.x * blockDim.x + threadIdx.x;
    for (; i < E; i += gridDim.x * blockDim.x) atomicAdd(&deg[dst[i]], 1);
}

__global__ __launch_bounds__(1024) void scan_kernel(const int* __restrict__ deg,
                                                    int* __restrict__ rowptr, int N) {
    __shared__ int sums[1024];
    int t = threadIdx.x;
    int chunk = (N + 1023) >> 10;
    int lo = t * chunk;
    int hi = lo + chunk; if (hi > N) hi = N;
    if (lo > N) lo = N;
    int s = 0;
    for (int i = lo; i < hi; ++i) s += deg[i];
    sums[t] = s;
    __syncthreads();
    for (int off = 1; off < 1024; off <<= 1) {
        int v = (t >= off) ? sums[t - off] : 0;
        __syncthreads();
        sums[t] += v;
        __syncthreads();
    }
    int run = (t > 0) ? sums[t - 1] : 0;
    for (int i = lo; i < hi; ++i) { rowptr[i] = run; run += deg[i]; }
    if (t == 1023) rowptr[N] = run;
}

__global__ void dinv_kernel(const int* __restrict__ deg, float* __restrict__ dinv, int N) {
    int i = blockIdx.x * blockDim.x + threadIdx.x;
    for (; i < N; i += gridDim.x * blockDim.x)
        dinv[i] = rsqrtf((float)(deg[i] + 1));  // +1 self loop
}

__global__ void copy_kernel(const int* __restrict__ a, int* __restrict__ b, int n) {
    int i = blockIdx.x * blockDim.x + threadIdx.x;
    for (; i < n; i += gridDim.x * blockDim.x) b[i] = a[i];
}

__global__ void scatter_kernel(const int* __restrict__ src, const int* __restrict__ dst,
                               int E, int* __restrict__ cursor, int* __restrict__ csrc) {
    int i = blockIdx.x * blockDim.x + threadIdx.x;
    for (; i < E; i += gridDim.x * blockDim.x) {
        int d = dst[i];
        int pos = atomicAdd(&cursor[d], 1);
        csrc[pos] = src[i];
    }
}

// ---------------- weight pre-transpose + split ----------------

__global__ void wsplit_kernel(const float* __restrict__ W, int K, int Nout,
                              int Kp, ushort* __restrict__ Whi, ushort* __restrict__ Wlo) {
    int k = blockIdx.x * blockDim.x + threadIdx.x;
    int n = blockIdx.y;
    if (k >= Kp) return;
    float v = (k < K && n < Nout) ? W[(size_t)k * Nout + n] : 0.f;
    __bf16 h = (__bf16)v;
    ushort hb = __builtin_bit_cast(ushort, h);
    float hf = __builtin_bit_cast(float, (unsigned)hb << 16);
    __bf16 l = (__bf16)(v - hf);
    Whi[(size_t)n * Kp + k] = hb;
    Wlo[(size_t)n * Kp + k] = __builtin_bit_cast(ushort, l);
}

// ---------------- MFMA helpers ----------------

__device__ inline f32x4 mfma16(bf16x8 a, bf16x8 b, f32x4 c) {
    return __builtin_amdgcn_mfma_f32_16x16x32_bf16(a, b, c, 0, 0, 0);
}

__device__ inline void split8(f32x4 a0, f32x4 a1, u16x8& hi, u16x8& lo) {
    float af[8] = {a0[0], a0[1], a0[2], a0[3], a1[0], a1[1], a1[2], a1[3]};
#pragma unroll
    for (int e = 0; e < 8; ++e) {
        __bf16 h = (__bf16)af[e];
        ushort hb = __builtin_bit_cast(ushort, h);
        float hf = __builtin_bit_cast(float, (unsigned)hb << 16);
        __bf16 l = (__bf16)(af[e] - hf);
        hi[e] = hb;
        lo[e] = __builtin_bit_cast(ushort, l);
    }
}

// ---------------- layer-0 GEMM (fp32 A, LDS split, 2-barrier K32) ----------------

template<int WM, int WN>
__global__ __launch_bounds__(WM * WN * 64) void gemm_t(
    const float* __restrict__ A, int lda, int Arows,
    const ushort* __restrict__ Bhi, const ushort* __restrict__ Blo, int Kp,
    const float* __restrict__ dinv, int N,
    float* __restrict__ C, int ldc)
{
    constexpr int BM = WM * 64;
    constexpr int T = WM * WN * 64;
    constexpr int SROW = BM + 2;
    __shared__ ushort Ah[4 * SROW * 8];
    __shared__ ushort Al[4 * SROW * 8];

    const int tid = threadIdx.x;
    const int lane = tid & 63;
    const int wave = tid >> 6;
    const int wm = (WM == 1) ? 0 : (wave % WM);
    const int wn = (WM == 1) ? wave : (wave / WM);
    const int m0 = blockIdx.x * BM;
    const int kg = lane >> 4;
    const int l16 = lane & 15;

    const ushort* bp[4];
#pragma unroll
    for (int fn = 0; fn < 4; ++fn) {
        int n = wn * 64 + fn * 16 + l16;
        bp[fn] = Bhi + (size_t)n * Kp + kg * 8;
    }
    const size_t lo_off = (size_t)(Blo - Bhi);

    f32x4 acc[4][4];
#pragma unroll
    for (int i = 0; i < 4; ++i)
#pragma unroll
        for (int j = 0; j < 4; ++j) acc[i][j] = (f32x4)0.f;

    for (int k0 = 0; k0 < Kp; k0 += 32) {
        for (int j = tid; j < BM * 4; j += T) {
            int row = j >> 2, jk = j & 3;
            int gr = m0 + row; if (gr > Arows - 1) gr = Arows - 1;
            const float* ap = A + (size_t)gr * lda + k0 + jk * 8;
            f32x4 a0 = *(const f32x4*)ap;
            f32x4 a1 = *(const f32x4*)(ap + 4);
            u16x8 hi, lo;
            split8(a0, a1, hi, lo);
            int idx = (jk * SROW + row) * 8;
            *(u16x8*)&Ah[idx] = hi;
            *(u16x8*)&Al[idx] = lo;
        }
        __syncthreads();
        bf16x8 bh[4], bl[4], ah[4], al[4];
#pragma unroll
        for (int fn = 0; fn < 4; ++fn) {
            bh[fn] = *(const bf16x8*)(bp[fn] + k0);
            bl[fn] = *(const bf16x8*)(bp[fn] + lo_off + k0);
        }
#pragma unroll
        for (int fm = 0; fm < 4; ++fm) {
            int idx = (kg * SROW + wm * 64 + fm * 16 + l16) * 8;
            ah[fm] = *(const bf16x8*)&Ah[idx];
            al[fm] = *(const bf16x8*)&Al[idx];
        }
#pragma unroll
        for (int fm = 0; fm < 4; ++fm)
#pragma unroll
            for (int fn = 0; fn < 4; ++fn) {
                acc[fm][fn] = mfma16(ah[fm], bh[fn], acc[fm][fn]);
                acc[fm][fn] = mfma16(ah[fm], bl[fn], acc[fm][fn]);
                acc[fm][fn] = mfma16(al[fm], bh[fn], acc[fm][fn]);
            }
        __syncthreads();
    }

#pragma unroll
    for (int fm = 0; fm < 4; ++fm)
#pragma unroll
        for (int fn = 0; fn < 4; ++fn) {
            int col = wn * 64 + fn * 16 + l16;
            if (col < ldc) {
#pragma unroll
                for (int r = 0; r < 4; ++r) {
                    int row = m0 + wm * 64 + fm * 16 + kg * 4 + r;
                    float dv = (row < N) ? dinv[row] : 0.f;
                    C[(size_t)row * ldc + col] = acc[fm][fn][r] * dv;
                }
            }
        }
}

// ------- layers 1-4 GEMM (pre-split bf16 A, copy-only staging, K32) -------

template<int WM, int WN>
__global__ __launch_bounds__(WM * WN * 64) void gemm_ps(
    const ushort* __restrict__ Ahi, const ushort* __restrict__ Alo, int lda, int Arows,
    const ushort* __restrict__ Bhi, const ushort* __restrict__ Blo, int Kp,
    const float* __restrict__ dinv, int N,
    float* __restrict__ C, int ldc)
{
    constexpr int BM = WM * 64;
    constexpr int T = WM * WN * 64;
    constexpr int SROW = BM + 2;
    __shared__ ushort Ah[4 * SROW * 8];
    __shared__ ushort Al[4 * SROW * 8];

    const int tid = threadIdx.x;
    const int lane = tid & 63;
    const int wave = tid >> 6;
    const int wm = (WM == 1) ? 0 : (wave % WM);
    const int wn = (WM == 1) ? wave : (wave / WM);
    const int m0 = blockIdx.x * BM;
    const int kg = lane >> 4;
    const int l16 = lane & 15;

    const size_t alo = (size_t)(Alo - Ahi);
    const ushort* bp[4];
#pragma unroll
    for (int fn = 0; fn < 4; ++fn) {
        int n = wn * 64 + fn * 16 + l16;
        bp[fn] = Bhi + (size_t)n * Kp + kg * 8;
    }
    const size_t blo = (size_t)(Blo - Bhi);

    f32x4 acc[4][4];
#pragma unroll
    for (int i = 0; i < 4; ++i)
#pragma unroll
        for (int j = 0; j < 4; ++j) acc[i][j] = (f32x4)0.f;

    for (int k0 = 0; k0 < Kp; k0 += 32) {
        // staging = pure 16B copies (no VALU split)
        for (int j = tid; j < BM * 4; j += T) {
            int row = j >> 2, jk = j & 3;
            int gr = m0 + row; if (gr > Arows - 1) gr = Arows - 1;
            const ushort* s = Ahi + (size_t)gr * lda + k0 + jk * 8;
            int idx = (jk * SROW + row) * 8;
            *(u16x8*)&Ah[idx] = *(const u16x8*)s;
            *(u16x8*)&Al[idx] = *(const u16x8*)(s + alo);
        }
        __syncthreads();
        bf16x8 bh[4], bl[4], ah[4], al[4];
#pragma unroll
        for (int fn = 0; fn < 4; ++fn) {
            bh[fn] = *(const bf16x8*)(bp[fn] + k0);
            bl[fn] = *(const bf16x8*)(bp[fn] + blo + k0);
        }
#pragma unroll
        for (int fm = 0; fm < 4; ++fm) {
            int idx = (kg * SROW + wm * 64 + fm * 16 + l16) * 8;
            ah[fm] = *(const bf16x8*)&Ah[idx];
            al[fm] = *(const bf16x8*)&Al[idx];
        }
#pragma unroll
        for (int fm = 0; fm < 4; ++fm)
#pragma unroll
            for (int fn = 0; fn < 4; ++fn) {
                acc[fm][fn] = mfma16(ah[fm], bh[fn], acc[fm][fn]);
                acc[fm][fn] = mfma16(ah[fm], bl[fn], acc[fm][fn]);
                acc[fm][fn] = mfma16(al[fm], bh[fn], acc[fm][fn]);
            }
        __syncthreads();
    }

#pragma unroll
    for (int fm = 0; fm < 4; ++fm)
#pragma unroll
        for (int fn = 0; fn < 4; ++fn) {
            int col = wn * 64 + fn * 16 + l16;
            if (col < ldc) {
#pragma unroll
                for (int r = 0; r < 4; ++r) {
                    int row = m0 + wm * 64 + fm * 16 + kg * 4 + r;
                    float dv = (row < N) ? dinv[row] : 0.f;
                    C[(size_t)row * ldc + col] = acc[fm][fn][r] * dv;
                }
            }
        }
}

// ---------------- CSR aggregation ----------------
// s = dinv[i]*(g[i] + sum_s g[s]) + bias; ReLU; emit split bf16 (next A) or
// fp32 (final).  Flat mapping node = gt / ND4T (compile-time divisor).

template<int ND4T, bool FIN>
__global__ __launch_bounds__(256) void agg_t(
    const float* __restrict__ g, int ld4,
    const int* __restrict__ rowptr, const int* __restrict__ csrc,
    const float* __restrict__ dinv, const float* __restrict__ bias,
    int D, int N,
    ushort* __restrict__ Ahi, ushort* __restrict__ Alo, int ldo,
    float* __restrict__ outF, int ldof)
{
    unsigned gt = blockIdx.x * 256u + threadIdx.x;
    unsigned node = gt / (unsigned)ND4T;
    unsigned f4 = gt - node * (unsigned)ND4T;
    if (node >= (unsigned)N) return;

    const f32x4* g4 = (const f32x4*)g;
    const unsigned l4 = (unsigned)ld4;

    f32x4 a0 = g4[(size_t)node * l4 + f4];   // self term
    f32x4 a1 = (f32x4)0.f, a2 = (f32x4)0.f, a3 = (f32x4)0.f;
    int beg = rowptr[node], end = rowptr[node + 1];
    int j = beg;
    for (; j + 3 < end; j += 4) {
        unsigned s0 = csrc[j], s1 = csrc[j + 1], s2 = csrc[j + 2], s3 = csrc[j + 3];
        a0 += g4[(size_t)s0 * l4 + f4];
        a1 += g4[(size_t)s1 * l4 + f4];
        a2 += g4[(size_t)s2 * l4 + f4];
        a3 += g4[(size_t)s3 * l4 + f4];
    }
    for (; j < end; ++j) a0 += g4[(size_t)csrc[j] * l4 + f4];

    f32x4 s = (a0 + a1) + (a2 + a3);
    float di = dinv[node];

    if (FIN) {
#pragma unroll
        for (int e = 0; e < 4; ++e) {
            int f = (int)f4 * 4 + e;
            if (f < D) outF[(size_t)node * ldof + f] = fmaf(di, s[e], bias[f]);
        }
    } else {
        u16x4 hv, lv;
#pragma unroll
        for (int e = 0; e < 4; ++e) {
            int f = (int)f4 * 4 + e;
            float val = 0.f;
            if (f < D) val = fmaxf(fmaf(di, s[e], bias[f]), 0.f);
            __bf16 h = (__bf16)val;
            ushort hb = __builtin_bit_cast(ushort, h);
            float hf = __builtin_bit_cast(float, (unsigned)hb << 16);
            __bf16 l = (__bf16)(val - hf);
            hv[e] = hb;
            lv[e] = __builtin_bit_cast(ushort, l);
        }
        *(u16x4*)(Ahi + (size_t)node * ldo + f4 * 4) = hv;
        *(u16x4*)(Alo + (size_t)node * ldo + f4 * 4) = lv;
    }
}

// ---------------- host launcher ----------------

extern "C" void kernel_launch(void* const* d_in, const int* in_sizes, int n_in,
                              void* d_out, int out_size, void* d_ws, size_t ws_size,
                              hipStream_t stream) {
    const float* x = (const float*)d_in[0];
    const int* ei = (const int*)d_in[1];
    int E = in_sizes[1] / 2;
    int N = in_sizes[0] / GDIMS[0];
    int Mp = ((N + 255) / 256) * 256;
    const int* src = ei;
    const int* dst = ei + E;

    const float* W[5];
    const float* bia[5];
    for (int i = 0; i < 5; ++i) {
        W[i] = (const float*)d_in[2 + 2 * i];
        bia[i] = (const float*)d_in[3 + 2 * i];
    }

    char* ws = (char*)d_ws;
    size_t off = 0;
    auto alloc = [&](size_t bytes) -> void* {
        void* p = ws + off;
        off += (bytes + 255) & ~(size_t)255;
        return p;
    };
    int* deg = (int*)alloc((size_t)N * 4);
    int* rowptr = (int*)alloc((size_t)(N + 1) * 4);
    int* cursor = (int*)alloc((size_t)N * 4);
    float* dinv = (float*)alloc((size_t)N * 4);
    int* csrc = (int*)alloc((size_t)E * 4);
    float* g = (float*)alloc((size_t)Mp * 224 * 4);
    ushort* Ahi = (ushort*)alloc((size_t)Mp * 224 * 2);
    ushort* Alo = (ushort*)alloc((size_t)Mp * 224 * 2);
    ushort* Whi[5];
    ushort* Wlo[5];
    int NB[5] = {256, 192, 128, 128, 64};
    int KP[5] = {512, 224, 192, 128, 96};
    for (int l = 0; l < 5; ++l) {
        Whi[l] = (ushort*)alloc((size_t)NB[l] * KP[l] * 2);
        Wlo[l] = (ushort*)alloc((size_t)NB[l] * KP[l] * 2);
    }
    (void)ws_size;

    // graph preprocessing
    zero_kernel<<<1024, 256, 0, stream>>>(deg, N);
    hist_kernel<<<2048, 256, 0, stream>>>(dst, E, deg);
    scan_kernel<<<1, 1024, 0, stream>>>(deg, rowptr, N);
    dinv_kernel<<<512, 256, 0, stream>>>(deg, dinv, N);
    copy_kernel<<<512, 256, 0, stream>>>(rowptr, cursor, N);
    scatter_kernel<<<2048, 256, 0, stream>>>(src, dst, E, cursor, csrc);

    // weight split
    for (int l = 0; l < 5; ++l) {
        dim3 gw((KP[l] + 255) / 256, NB[l]);
        wsplit_kernel<<<gw, 256, 0, stream>>>(W[l], GDIMS[l], GDIMS[l + 1], KP[l],
                                              Whi[l], Wlo[l]);
    }

    auto aggBlocks = [&](int nd4t) { return (unsigned)(((size_t)N * nd4t + 255) / 256); };

    // ---- layer 0 ----
    gemm_t<1, 4><<<Mp / 64, 256, 0, stream>>>(x, 512, N, Whi[0], Wlo[0], 512,
                                              dinv, N, g, 224);
    agg_t<56, false><<<aggBlocks(56), 256, 0, stream>>>(g, 56, rowptr, csrc, dinv,
                                                        bia[0], 200, N, Ahi, Alo, 224,
                                                        nullptr, 0);
    // ---- layer 1 ----
    gemm_ps<1, 3><<<Mp / 64, 192, 0, stream>>>(Ahi, Alo, 224, N, Whi[1], Wlo[1], 224,
                                               dinv, N, g, 192);
    agg_t<48, false><<<aggBlocks(48), 256, 0, stream>>>(g, 48, rowptr, csrc, dinv,
                                                        bia[1], 175, N, Ahi, Alo, 192,
                                                        nullptr, 0);
    // ---- layer 2 ----
    gemm_ps<2, 2><<<Mp / 128, 256, 0, stream>>>(Ahi, Alo, 192, N, Whi[2], Wlo[2], 192,
                                                dinv, N, g, 128);
    agg_t<32, false><<<aggBlocks(32), 256, 0, stream>>>(g, 32, rowptr, csrc, dinv,
                                                        bia[2], 125, N, Ahi, Alo, 128,
                                                        nullptr, 0);
    // ---- layer 3 ----
    gemm_ps<2, 2><<<Mp / 128, 256, 0, stream>>>(Ahi, Alo, 128, N, Whi[3], Wlo[3], 128,
                                                dinv, N, g, 96);
    agg_t<24, false><<<aggBlocks(24), 256, 0, stream>>>(g, 24, rowptr, csrc, dinv,
                                                        bia[3], 75, N, Ahi, Alo, 96,
                                                        nullptr, 0);
    // ---- layer 4 (final, fp32 out) ----
    gemm_ps<4, 1><<<Mp / 256, 256, 0, stream>>>(Ahi, Alo, 96, N, Whi[4], Wlo[4], 96,
                                                dinv, N, g, 64);
    agg_t<13, true><<<aggBlocks(13), 256, 0, stream>>>(g, 16, rowptr, csrc, dinv,
                                                       bia[4], 50, N, nullptr, nullptr, 0,
                                                       (float*)d_out, 50);
    (void)out_size; (void)n_in;
}